// Round 2
// baseline (3214.983 us; speedup 1.0000x reference)
//
#include <hip/hip_runtime.h>

#define NN 50000
#define NE 800000
#define DIN 128
#define DHID 256
#define DOUT 128

// ---------------- threefry2x32, JAX-exact, key = (0, 42) ----------------
__device__ __forceinline__ unsigned tf_rotl(unsigned x, int r) {
  return (x << r) | (x >> (32 - r));
}

__device__ __forceinline__ void threefry_0_42(unsigned x0, unsigned x1,
                                              unsigned& o0, unsigned& o1) {
  const unsigned k0 = 0u, k1 = 42u;
  const unsigned k2 = k0 ^ k1 ^ 0x1BD11BDAu;
  x0 += k0; x1 += k1;
#define TF_R(r) { x0 += x1; x1 = tf_rotl(x1, (r)); x1 ^= x0; }
  TF_R(13) TF_R(15) TF_R(26) TF_R(6)
  x0 += k1; x1 += k2 + 1u;
  TF_R(17) TF_R(29) TF_R(16) TF_R(24)
  x0 += k2; x1 += k0 + 2u;
  TF_R(13) TF_R(15) TF_R(26) TF_R(6)
  x0 += k0; x1 += k1 + 3u;
  TF_R(17) TF_R(29) TF_R(16) TF_R(24)
  x0 += k1; x1 += k2 + 4u;
  TF_R(13) TF_R(15) TF_R(26) TF_R(6)
  x0 += k2; x1 += k0 + 5u;
#undef TF_R
  o0 = x0; o1 = x1;
}

// JAX partitionable threefry (default since 0.4.30 / JEP 18206):
// per-element counter (hi32(i), lo32(i)); 32-bit draw = o0 ^ o1.
__device__ __forceinline__ float dropout_scale(unsigned flat) {
  unsigned o0, o1;
  threefry_0_42(0u, flat, o0, o1);
  unsigned bits = o0 ^ o1;
  float u = __uint_as_float((bits >> 9) | 0x3f800000u) - 1.0f;
  return (u < 0.9f) ? (1.0f / 0.9f) : 0.0f;
}

// ---------------- utility kernels ----------------
__global__ void zero4_k(float4* p, int n4) {
  int i = blockIdx.x * blockDim.x + threadIdx.x;
  if (i < n4) p[i] = make_float4(0.f, 0.f, 0.f, 0.f);
}

__global__ void count_k(const int* __restrict__ dst, unsigned* __restrict__ cnt) {
  int e = blockIdx.x * blockDim.x + threadIdx.x;
  if (e < NE) {
    unsigned d = (unsigned)dst[e];
    if (d < (unsigned)NN) atomicAdd(&cnt[d], 1u);
  }
}

__global__ void inv_k(const unsigned* __restrict__ cnt, float* __restrict__ inv) {
  int n = blockIdx.x * blockDim.x + threadIdx.x;
  if (n < NN) inv[n] = 1.0f / fmaxf((float)cnt[n], 1.0f);
}

// scatter-add: agg[dst] += V[src] over 128 features, 32 threads/edge * float4
__global__ void scatter_k(const int* __restrict__ src, const int* __restrict__ dst,
                          const float* __restrict__ V, float* __restrict__ agg) {
  int gid = blockIdx.x * blockDim.x + threadIdx.x;
  int e = gid >> 5;
  if (e >= NE) return;
  int f = (gid & 31) << 2;
  unsigned s = (unsigned)src[e], d = (unsigned)dst[e];
  if (s >= (unsigned)NN || d >= (unsigned)NN) return;
  const float4 v = *(const float4*)(V + (size_t)s * 128 + f);
  float* o = agg + (size_t)d * 128 + f;
  atomicAdd(o + 0, v.x);
  atomicAdd(o + 1, v.y);
  atomicAdd(o + 2, v.z);
  atomicAdd(o + 3, v.w);
}

// scatter-add scaled: out[dst] += V[src] * inv[dst]
__global__ void scatter_scaled_k(const int* __restrict__ src, const int* __restrict__ dst,
                                 const float* __restrict__ V, const float* __restrict__ inv,
                                 float* __restrict__ out) {
  int gid = blockIdx.x * blockDim.x + threadIdx.x;
  int e = gid >> 5;
  if (e >= NE) return;
  int f = (gid & 31) << 2;
  unsigned s = (unsigned)src[e], d = (unsigned)dst[e];
  if (s >= (unsigned)NN || d >= (unsigned)NN) return;
  float sc = inv[d];
  const float4 v = *(const float4*)(V + (size_t)s * 128 + f);
  float* o = out + (size_t)d * 128 + f;
  atomicAdd(o + 0, v.x * sc);
  atomicAdd(o + 1, v.y * sc);
  atomicAdd(o + 2, v.z * sc);
  atomicAdd(o + 3, v.w * sc);
}

// ---------------- GEMM 1: h = dropout(relu([x | agg*inv] @ [Wr1; Wl1] + b1)) ----------------
#define BM 64
#define BN 64
#define BK 32

__global__ __launch_bounds__(256) void gemm1_k(
    const float* __restrict__ x, const float* __restrict__ agg,
    const float* __restrict__ inv, const float* __restrict__ Wl,
    const float* __restrict__ Wr, const float* __restrict__ b,
    float* __restrict__ h) {
  __shared__ float As[BK][BM + 1];
  __shared__ float Bs[BK][BN];
  const int tid = threadIdx.x;
  const int tx = tid & 15, ty = tid >> 4;
  const int m0 = blockIdx.x * BM;
  const int j0 = blockIdx.y * BN;
  float acc[4][4] = {};

  for (int k0 = 0; k0 < DHID; k0 += BK) {
#pragma unroll
    for (int r = 0; r < 8; ++r) {
      int idx = r * 256 + tid;
      int m = idx >> 5, kk = idx & 31;
      int row = m0 + m, k = k0 + kk;
      float v = 0.f;
      if (row < NN) {
        if (k < 128) v = x[(size_t)row * 128 + k];
        else         v = agg[(size_t)row * 128 + (k - 128)] * inv[row];
      }
      As[kk][m] = v;
    }
#pragma unroll
    for (int r = 0; r < 8; ++r) {
      int idx = r * 256 + tid;
      int kk = idx >> 6, jj = idx & 63;
      int k = k0 + kk, j = j0 + jj;
      Bs[kk][jj] = (k < 128) ? Wr[(size_t)k * 256 + j]
                             : Wl[(size_t)(k - 128) * 256 + j];
    }
    __syncthreads();
#pragma unroll
    for (int kk = 0; kk < BK; ++kk) {
      float a[4], bb[4];
#pragma unroll
      for (int i = 0; i < 4; ++i) a[i] = As[kk][ty * 4 + i];
#pragma unroll
      for (int j = 0; j < 4; ++j) bb[j] = Bs[kk][tx * 4 + j];
#pragma unroll
      for (int i = 0; i < 4; ++i)
#pragma unroll
        for (int j = 0; j < 4; ++j)
          acc[i][j] = fmaf(a[i], bb[j], acc[i][j]);
    }
    __syncthreads();
  }

#pragma unroll
  for (int i = 0; i < 4; ++i) {
    int row = m0 + ty * 4 + i;
    if (row >= NN) continue;
#pragma unroll
    for (int j = 0; j < 4; ++j) {
      int col = j0 + tx * 4 + j;
      float v = acc[i][j] + b[col];
      v = fmaxf(v, 0.f);
      unsigned flat = (unsigned)row * 256u + (unsigned)col;
      v *= dropout_scale(flat);
      h[flat] = v;
    }
  }
}

// ---------------- GEMM 2: P = h @ Wl2 ; out = h @ Wr2 + b2 ----------------
__global__ __launch_bounds__(256) void gemm2_k(
    const float* __restrict__ h, const float* __restrict__ Wl,
    const float* __restrict__ Wr, const float* __restrict__ b,
    float* __restrict__ P, float* __restrict__ out) {
  __shared__ float As[BK][BM + 1];
  __shared__ float Bs[BK][BN];
  const int tid = threadIdx.x;
  const int tx = tid & 15, ty = tid >> 4;
  const int m0 = blockIdx.x * BM;
  const int j0 = blockIdx.y * BN;  // j in [0,256): <128 -> P, >=128 -> out
  float acc[4][4] = {};

  for (int k0 = 0; k0 < DHID; k0 += BK) {
#pragma unroll
    for (int r = 0; r < 8; ++r) {
      int idx = r * 256 + tid;
      int m = idx >> 5, kk = idx & 31;
      int row = m0 + m, k = k0 + kk;
      As[kk][m] = (row < NN) ? h[(size_t)row * 256 + k] : 0.f;
    }
#pragma unroll
    for (int r = 0; r < 8; ++r) {
      int idx = r * 256 + tid;
      int kk = idx >> 6, jj = idx & 63;
      int k = k0 + kk, j = j0 + jj;
      Bs[kk][jj] = (j < 128) ? Wl[(size_t)k * 128 + j]
                             : Wr[(size_t)k * 128 + (j - 128)];
    }
    __syncthreads();
#pragma unroll
    for (int kk = 0; kk < BK; ++kk) {
      float a[4], bb[4];
#pragma unroll
      for (int i = 0; i < 4; ++i) a[i] = As[kk][ty * 4 + i];
#pragma unroll
      for (int j = 0; j < 4; ++j) bb[j] = Bs[kk][tx * 4 + j];
#pragma unroll
      for (int i = 0; i < 4; ++i)
#pragma unroll
        for (int j = 0; j < 4; ++j)
          acc[i][j] = fmaf(a[i], bb[j], acc[i][j]);
    }
    __syncthreads();
  }

#pragma unroll
  for (int i = 0; i < 4; ++i) {
    int row = m0 + ty * 4 + i;
    if (row >= NN) continue;
#pragma unroll
    for (int j = 0; j < 4; ++j) {
      int col = j0 + tx * 4 + j;
      if (col < 128) {
        P[(size_t)row * 128 + col] = acc[i][j];
      } else {
        out[(size_t)row * 128 + (col - 128)] = acc[i][j] + b[col - 128];
      }
    }
  }
}

// ---------------- launch ----------------
extern "C" void kernel_launch(void* const* d_in, const int* in_sizes, int n_in,
                              void* d_out, int out_size, void* d_ws, size_t ws_size,
                              hipStream_t stream) {
  const float* x   = (const float*)d_in[0];
  const int*   ei  = (const int*)d_in[1];
  const float* Wl1 = (const float*)d_in[2];
  const float* Wr1 = (const float*)d_in[3];
  const float* b1  = (const float*)d_in[4];
  const float* Wl2 = (const float*)d_in[5];
  const float* Wr2 = (const float*)d_in[6];
  const float* b2  = (const float*)d_in[7];
  float* out = (float*)d_out;

  const int* src = ei;
  const int* dst = ei + NE;

  // workspace layout (bytes), peak ~77.3 MB:
  // cnt:  [0, 200000)            (50000 u32)
  // inv:  [0x40000, +200000)     (50000 f32)
  // bufA: [0x80000, +25.6MB)     agg1 (layer1), then P (layer2) — disjoint lifetimes
  // h:    [bufA_end, +51.2MB)
  char* ws = (char*)d_ws;
  unsigned* cnt = (unsigned*)ws;
  float* inv  = (float*)(ws + 0x40000);
  float* bufA = (float*)(ws + 0x80000);
  float* h    = (float*)(ws + 0x80000 + (size_t)NN * 128 * 4);

  const int TPB = 256;
  // zero cnt + agg1
  zero4_k<<<(NN * 4 / 16 + TPB - 1) / TPB, TPB, 0, stream>>>((float4*)cnt, NN * 4 / 16);
  zero4_k<<<(NN * 128 / 4 + TPB - 1) / TPB, TPB, 0, stream>>>((float4*)bufA, NN * 128 / 4);

  count_k<<<(NE + TPB - 1) / TPB, TPB, 0, stream>>>(dst, cnt);
  inv_k<<<(NN + TPB - 1) / TPB, TPB, 0, stream>>>(cnt, inv);

  // layer 1: aggregate x into bufA, then fused GEMM + relu + dropout -> h
  scatter_k<<<(NE * 32 + TPB - 1) / TPB, TPB, 0, stream>>>(src, dst, x, bufA);
  dim3 g1((NN + BM - 1) / BM, DHID / BN);
  gemm1_k<<<g1, TPB, 0, stream>>>(x, bufA, inv, Wl1, Wr1, b1, h);

  // layer 2: P = h@Wl2 (into bufA), out = h@Wr2+b2; then out[d] += P[s]*inv[d]
  gemm2_k<<<g1, TPB, 0, stream>>>(h, Wl2, Wr2, b2, bufA, out);
  scatter_scaled_k<<<(NE * 32 + TPB - 1) / TPB, TPB, 0, stream>>>(src, dst, bufA, inv, out);
}

// Round 3
// 695.033 us; speedup vs baseline: 4.6257x; 4.6257x over previous
//
#include <hip/hip_runtime.h>

#define NN 50000
#define NE 800000
#define DIN 128
#define DHID 256
#define DOUT 128

// ---------------- threefry2x32, JAX partitionable, key = (0, 42) ----------------
__device__ __forceinline__ unsigned tf_rotl(unsigned x, int r) {
  return (x << r) | (x >> (32 - r));
}

__device__ __forceinline__ void threefry_0_42(unsigned x0, unsigned x1,
                                              unsigned& o0, unsigned& o1) {
  const unsigned k0 = 0u, k1 = 42u;
  const unsigned k2 = k0 ^ k1 ^ 0x1BD11BDAu;
  x0 += k0; x1 += k1;
#define TF_R(r) { x0 += x1; x1 = tf_rotl(x1, (r)); x1 ^= x0; }
  TF_R(13) TF_R(15) TF_R(26) TF_R(6)
  x0 += k1; x1 += k2 + 1u;
  TF_R(17) TF_R(29) TF_R(16) TF_R(24)
  x0 += k2; x1 += k0 + 2u;
  TF_R(13) TF_R(15) TF_R(26) TF_R(6)
  x0 += k0; x1 += k1 + 3u;
  TF_R(17) TF_R(29) TF_R(16) TF_R(24)
  x0 += k1; x1 += k2 + 4u;
  TF_R(13) TF_R(15) TF_R(26) TF_R(6)
  x0 += k2; x1 += k0 + 5u;
#undef TF_R
  o0 = x0; o1 = x1;
}

__device__ __forceinline__ float dropout_scale(unsigned flat) {
  unsigned o0, o1;
  threefry_0_42(0u, flat, o0, o1);
  unsigned bits = o0 ^ o1;
  float u = __uint_as_float((bits >> 9) | 0x3f800000u) - 1.0f;
  return (u < 0.9f) ? (1.0f / 0.9f) : 0.0f;
}

// ---------------- CSR build ----------------
__global__ void zero4_k(float4* p, int n4) {
  int i = blockIdx.x * blockDim.x + threadIdx.x;
  if (i < n4) p[i] = make_float4(0.f, 0.f, 0.f, 0.f);
}

__global__ void count_k(const int* __restrict__ dst, unsigned* __restrict__ cnt) {
  int e = blockIdx.x * blockDim.x + threadIdx.x;
  if (e < NE) {
    unsigned d = (unsigned)dst[e];
    if (d < (unsigned)NN) atomicAdd(&cnt[d], 1u);
  }
}

__global__ void inv_k(const unsigned* __restrict__ cnt, float* __restrict__ inv) {
  int n = blockIdx.x * blockDim.x + threadIdx.x;
  if (n < NN) inv[n] = 1.0f / fmaxf((float)cnt[n], 1.0f);
}

// single-block Hillis-Steele scan over 50000 counts -> exclusive rowptr
__global__ __launch_bounds__(1024) void scan_k(const unsigned* __restrict__ cnt,
                                               unsigned* __restrict__ rowptr) {
  __shared__ unsigned s[1024];
  __shared__ unsigned carry;
  if (threadIdx.x == 0) carry = 0;
  __syncthreads();
  for (int base = 0; base < NN; base += 1024) {
    int i = base + threadIdx.x;
    unsigned v = (i < NN) ? cnt[i] : 0u;
    s[threadIdx.x] = v;
    __syncthreads();
    for (int off = 1; off < 1024; off <<= 1) {
      unsigned t = (threadIdx.x >= (unsigned)off) ? s[threadIdx.x - off] : 0u;
      __syncthreads();
      s[threadIdx.x] += t;
      __syncthreads();
    }
    if (i < NN) rowptr[i] = carry + (s[threadIdx.x] - v);
    __syncthreads();
    if (threadIdx.x == 1023) carry += s[1023];
    __syncthreads();
  }
  if (threadIdx.x == 0) rowptr[NN] = carry;
}

__global__ void fill_k(const int* __restrict__ src, const int* __restrict__ dst,
                       const unsigned* __restrict__ rowptr, unsigned* __restrict__ cursor,
                       int* __restrict__ esrc) {
  int e = blockIdx.x * blockDim.x + threadIdx.x;
  if (e >= NE) return;
  unsigned d = (unsigned)dst[e];
  if (d >= (unsigned)NN) return;
  unsigned pos = atomicAdd(&cursor[d], 1u);
  esrc[rowptr[d] + pos] = src[e];
}

// ---------------- pull-style aggregation (no atomics) ----------------
// one wave per node; 64 lanes x float2 = full 128-float row per edge
__global__ __launch_bounds__(256) void gather_mean_k(
    const int* __restrict__ esrc, const unsigned* __restrict__ rowptr,
    const float* __restrict__ inv, const float* __restrict__ V,
    float* __restrict__ mean) {
  int node = blockIdx.x * 4 + (threadIdx.x >> 6);
  if (node >= NN) return;
  int lane = threadIdx.x & 63;
  unsigned beg = rowptr[node], end = rowptr[node + 1];
  const float2* Vv = (const float2*)V;
  float2 acc = {0.f, 0.f};
  unsigned t = beg;
  for (; t + 2 <= end; t += 2) {
    int s0 = esrc[t], s1 = esrc[t + 1];
    float2 v0 = Vv[(size_t)s0 * 64 + lane];
    float2 v1 = Vv[(size_t)s1 * 64 + lane];
    acc.x += v0.x + v1.x;
    acc.y += v0.y + v1.y;
  }
  if (t < end) {
    int s0 = esrc[t];
    float2 v0 = Vv[(size_t)s0 * 64 + lane];
    acc.x += v0.x;
    acc.y += v0.y;
  }
  float sc = inv[node];
  acc.x *= sc; acc.y *= sc;
  ((float2*)mean)[(size_t)node * 64 + lane] = acc;
}

// out[node] += mean_over_edges(P[src]) ; private RMW, no atomics
__global__ __launch_bounds__(256) void gather_add_k(
    const int* __restrict__ esrc, const unsigned* __restrict__ rowptr,
    const float* __restrict__ inv, const float* __restrict__ P,
    float* __restrict__ out) {
  int node = blockIdx.x * 4 + (threadIdx.x >> 6);
  if (node >= NN) return;
  int lane = threadIdx.x & 63;
  unsigned beg = rowptr[node], end = rowptr[node + 1];
  const float2* Pv = (const float2*)P;
  float2 acc = {0.f, 0.f};
  unsigned t = beg;
  for (; t + 2 <= end; t += 2) {
    int s0 = esrc[t], s1 = esrc[t + 1];
    float2 v0 = Pv[(size_t)s0 * 64 + lane];
    float2 v1 = Pv[(size_t)s1 * 64 + lane];
    acc.x += v0.x + v1.x;
    acc.y += v0.y + v1.y;
  }
  if (t < end) {
    int s0 = esrc[t];
    float2 v0 = Pv[(size_t)s0 * 64 + lane];
    acc.x += v0.x;
    acc.y += v0.y;
  }
  float sc = inv[node];
  float2* O = (float2*)out;
  float2 o = O[(size_t)node * 64 + lane];
  o.x += acc.x * sc;
  o.y += acc.y * sc;
  O[(size_t)node * 64 + lane] = o;
}

// ---------------- GEMM 1: h = dropout(relu([x | mean] @ [Wr1; Wl1] + b1)) ----------------
#define BM 64
#define BN 64
#define BK 32

__global__ __launch_bounds__(256) void gemm1_k(
    const float* __restrict__ x, const float* __restrict__ mean,
    const float* __restrict__ Wl, const float* __restrict__ Wr,
    const float* __restrict__ b, float* __restrict__ h) {
  __shared__ float As[BK][BM + 1];
  __shared__ float Bs[BK][BN];
  const int tid = threadIdx.x;
  const int tx = tid & 15, ty = tid >> 4;
  const int m0 = blockIdx.x * BM;
  const int j0 = blockIdx.y * BN;
  float acc[4][4] = {};

  for (int k0 = 0; k0 < DHID; k0 += BK) {
#pragma unroll
    for (int r = 0; r < 8; ++r) {
      int idx = r * 256 + tid;
      int m = idx >> 5, kk = idx & 31;
      int row = m0 + m, k = k0 + kk;
      float v = 0.f;
      if (row < NN) {
        if (k < 128) v = x[(size_t)row * 128 + k];
        else         v = mean[(size_t)row * 128 + (k - 128)];
      }
      As[kk][m] = v;
    }
#pragma unroll
    for (int r = 0; r < 8; ++r) {
      int idx = r * 256 + tid;
      int kk = idx >> 6, jj = idx & 63;
      int k = k0 + kk, j = j0 + jj;
      Bs[kk][jj] = (k < 128) ? Wr[(size_t)k * 256 + j]
                             : Wl[(size_t)(k - 128) * 256 + j];
    }
    __syncthreads();
#pragma unroll
    for (int kk = 0; kk < BK; ++kk) {
      float a[4], bb[4];
#pragma unroll
      for (int i = 0; i < 4; ++i) a[i] = As[kk][ty * 4 + i];
#pragma unroll
      for (int j = 0; j < 4; ++j) bb[j] = Bs[kk][tx * 4 + j];
#pragma unroll
      for (int i = 0; i < 4; ++i)
#pragma unroll
        for (int j = 0; j < 4; ++j)
          acc[i][j] = fmaf(a[i], bb[j], acc[i][j]);
    }
    __syncthreads();
  }

#pragma unroll
  for (int i = 0; i < 4; ++i) {
    int row = m0 + ty * 4 + i;
    if (row >= NN) continue;
#pragma unroll
    for (int j = 0; j < 4; ++j) {
      int col = j0 + tx * 4 + j;
      float v = acc[i][j] + b[col];
      v = fmaxf(v, 0.f);
      unsigned flat = (unsigned)row * 256u + (unsigned)col;
      v *= dropout_scale(flat);
      h[flat] = v;
    }
  }
}

// ---------------- GEMM 2: P = h @ Wl2 ; out = h @ Wr2 + b2 ----------------
__global__ __launch_bounds__(256) void gemm2_k(
    const float* __restrict__ h, const float* __restrict__ Wl,
    const float* __restrict__ Wr, const float* __restrict__ b,
    float* __restrict__ P, float* __restrict__ out) {
  __shared__ float As[BK][BM + 1];
  __shared__ float Bs[BK][BN];
  const int tid = threadIdx.x;
  const int tx = tid & 15, ty = tid >> 4;
  const int m0 = blockIdx.x * BM;
  const int j0 = blockIdx.y * BN;  // col<128 -> P, col>=128 -> out
  float acc[4][4] = {};

  for (int k0 = 0; k0 < DHID; k0 += BK) {
#pragma unroll
    for (int r = 0; r < 8; ++r) {
      int idx = r * 256 + tid;
      int m = idx >> 5, kk = idx & 31;
      int row = m0 + m, k = k0 + kk;
      As[kk][m] = (row < NN) ? h[(size_t)row * 256 + k] : 0.f;
    }
#pragma unroll
    for (int r = 0; r < 8; ++r) {
      int idx = r * 256 + tid;
      int kk = idx >> 6, jj = idx & 63;
      int k = k0 + kk, j = j0 + jj;
      Bs[kk][jj] = (j < 128) ? Wl[(size_t)k * 128 + j]
                             : Wr[(size_t)k * 128 + (j - 128)];
    }
    __syncthreads();
#pragma unroll
    for (int kk = 0; kk < BK; ++kk) {
      float a[4], bb[4];
#pragma unroll
      for (int i = 0; i < 4; ++i) a[i] = As[kk][ty * 4 + i];
#pragma unroll
      for (int j = 0; j < 4; ++j) bb[j] = Bs[kk][tx * 4 + j];
#pragma unroll
      for (int i = 0; i < 4; ++i)
#pragma unroll
        for (int j = 0; j < 4; ++j)
          acc[i][j] = fmaf(a[i], bb[j], acc[i][j]);
    }
    __syncthreads();
  }

#pragma unroll
  for (int i = 0; i < 4; ++i) {
    int row = m0 + ty * 4 + i;
    if (row >= NN) continue;
#pragma unroll
    for (int j = 0; j < 4; ++j) {
      int col = j0 + tx * 4 + j;
      if (col < 128) {
        P[(size_t)row * 128 + col] = acc[i][j];
      } else {
        out[(size_t)row * 128 + (col - 128)] = acc[i][j] + b[col - 128];
      }
    }
  }
}

// ---------------- launch ----------------
extern "C" void kernel_launch(void* const* d_in, const int* in_sizes, int n_in,
                              void* d_out, int out_size, void* d_ws, size_t ws_size,
                              hipStream_t stream) {
  const float* x   = (const float*)d_in[0];
  const int*   ei  = (const int*)d_in[1];
  const float* Wl1 = (const float*)d_in[2];
  const float* Wr1 = (const float*)d_in[3];
  const float* b1  = (const float*)d_in[4];
  const float* Wl2 = (const float*)d_in[5];
  const float* Wr2 = (const float*)d_in[6];
  const float* b2  = (const float*)d_in[7];
  float* out = (float*)d_out;

  const int* src = ei;
  const int* dst = ei + NE;

  // workspace layout (~81 MB):
  // rowptr: [0, 0x40000)           50001 u32
  // inv:    [0x40000, 0x80000)     50000 f32
  // cnt:    [0x80000, 0xC0000)     50000 u32 (reused as cursor after scan)
  // esrc:   [0xC0000, +3.2MB)      800000 i32
  // bufA:   [esrc_end, +25.6MB)    mean (layer1) then P (layer2)
  // h:      [bufA_end, +51.2MB)
  char* ws = (char*)d_ws;
  unsigned* rowptr = (unsigned*)ws;
  float*    inv    = (float*)(ws + 0x40000);
  unsigned* cnt    = (unsigned*)(ws + 0x80000);
  int*      esrc   = (int*)(ws + 0xC0000);
  float*    bufA   = (float*)(ws + 0xC0000 + (size_t)NE * 4);
  float*    h      = bufA + (size_t)NN * 128;

  const int TPB = 256;
  // CSR build
  zero4_k<<<(NN * 4 / 16 + TPB - 1) / TPB, TPB, 0, stream>>>((float4*)cnt, NN * 4 / 16);
  count_k<<<(NE + TPB - 1) / TPB, TPB, 0, stream>>>(dst, cnt);
  inv_k<<<(NN + TPB - 1) / TPB, TPB, 0, stream>>>(cnt, inv);
  scan_k<<<1, 1024, 0, stream>>>(cnt, rowptr);
  zero4_k<<<(NN * 4 / 16 + TPB - 1) / TPB, TPB, 0, stream>>>((float4*)cnt, NN * 4 / 16);  // cnt -> cursor
  fill_k<<<(NE + TPB - 1) / TPB, TPB, 0, stream>>>(src, dst, rowptr, cnt, esrc);

  // layer 1: mean-gather x -> bufA, fused GEMM + relu + dropout -> h
  gather_mean_k<<<(NN + 3) / 4, TPB, 0, stream>>>(esrc, rowptr, inv, x, bufA);
  dim3 g1((NN + BM - 1) / BM, DHID / BN);
  gemm1_k<<<g1, TPB, 0, stream>>>(x, bufA, Wl1, Wr1, b1, h);

  // layer 2: P = h@Wl2 (bufA), out = h@Wr2+b2; then out += mean-gather(P)
  gemm2_k<<<g1, TPB, 0, stream>>>(h, Wl2, Wr2, b2, bufA, out);
  gather_add_k<<<(NN + 3) / 4, TPB, 0, stream>>>(esrc, rowptr, inv, bufA, out);
}

// Round 5
// 338.947 us; speedup vs baseline: 9.4852x; 2.0506x over previous
//
#include <hip/hip_runtime.h>

#define NN 50000
#define NE 800000

typedef __attribute__((ext_vector_type(8))) short short8;
typedef __attribute__((ext_vector_type(4))) float f32x4;

// ---------------- bf16 helpers (RNE) ----------------
__device__ __forceinline__ unsigned short f2bf(float f) {
  union { float f; unsigned u; } v; v.f = f;
  unsigned r = (v.u + 0x7FFFu + ((v.u >> 16) & 1u)) >> 16;
  return (unsigned short)r;
}
__device__ __forceinline__ float bflo(unsigned u) {
  union { unsigned x; float f; } v; v.x = u << 16; return v.f;
}
__device__ __forceinline__ float bfhi(unsigned u) {
  union { unsigned x; float f; } v; v.x = u & 0xFFFF0000u; return v.f;
}

// ---------------- threefry2x32, JAX partitionable, key = (0, 42) ----------------
__device__ __forceinline__ unsigned tf_rotl(unsigned x, int r) {
  return (x << r) | (x >> (32 - r));
}
__device__ __forceinline__ void threefry_0_42(unsigned x0, unsigned x1,
                                              unsigned& o0, unsigned& o1) {
  const unsigned k0 = 0u, k1 = 42u;
  const unsigned k2 = k0 ^ k1 ^ 0x1BD11BDAu;
  x0 += k0; x1 += k1;
#define TF_R(r) { x0 += x1; x1 = tf_rotl(x1, (r)); x1 ^= x0; }
  TF_R(13) TF_R(15) TF_R(26) TF_R(6)
  x0 += k1; x1 += k2 + 1u;
  TF_R(17) TF_R(29) TF_R(16) TF_R(24)
  x0 += k2; x1 += k0 + 2u;
  TF_R(13) TF_R(15) TF_R(26) TF_R(6)
  x0 += k0; x1 += k1 + 3u;
  TF_R(17) TF_R(29) TF_R(16) TF_R(24)
  x0 += k1; x1 += k2 + 4u;
  TF_R(13) TF_R(15) TF_R(26) TF_R(6)
  x0 += k2; x1 += k0 + 5u;
#undef TF_R
  o0 = x0; o1 = x1;
}
__device__ __forceinline__ float dropout_scale(unsigned flat) {
  unsigned o0, o1;
  threefry_0_42(0u, flat, o0, o1);
  unsigned bits = o0 ^ o1;
  float u = __uint_as_float((bits >> 9) | 0x3f800000u) - 1.0f;
  return (u < 0.9f) ? (1.0f / 0.9f) : 0.0f;
}

// ---------------- prep: conversions / weight packing ----------------
__global__ void cvtx_k(const float4* __restrict__ x, uint2* __restrict__ xb, int n4) {
  int i = blockIdx.x * 256 + threadIdx.x;
  if (i >= n4) return;
  float4 v = x[i];
  uint2 o;
  o.x = (unsigned)f2bf(v.x) | ((unsigned)f2bf(v.y) << 16);
  o.y = (unsigned)f2bf(v.z) | ((unsigned)f2bf(v.w) << 16);
  xb[i] = o;
}

// W1t[n][k] (256x256 bf16): k<128 -> Wr1[k][n], else Wl1[k-128][n]
__global__ void mkw1_k(const float* __restrict__ Wl, const float* __restrict__ Wr,
                       unsigned short* __restrict__ Wt) {
  int idx = blockIdx.x * 256 + threadIdx.x;  // 65536
  int n = idx >> 8, k = idx & 255;
  float v = (k < 128) ? Wr[(size_t)k * 256 + n] : Wl[(size_t)(k - 128) * 256 + n];
  Wt[idx] = f2bf(v);
}

// W2t[n][k] (256x256 bf16): n<128 -> Wl2[k][n], else Wr2[k][n-128]
__global__ void mkw2_k(const float* __restrict__ Wl, const float* __restrict__ Wr,
                       unsigned short* __restrict__ Wt) {
  int idx = blockIdx.x * 256 + threadIdx.x;  // 65536
  int n = idx >> 8, k = idx & 255;
  float v = (n < 128) ? Wl[(size_t)k * 128 + n] : Wr[(size_t)k * 128 + (n - 128)];
  Wt[idx] = f2bf(v);
}

// ---------------- CSR build ----------------
__global__ void zero4_k(float4* p, int n4) {
  int i = blockIdx.x * blockDim.x + threadIdx.x;
  if (i < n4) p[i] = make_float4(0.f, 0.f, 0.f, 0.f);
}

__global__ void count_k(const int* __restrict__ dst, unsigned* __restrict__ cnt) {
  int e = blockIdx.x * blockDim.x + threadIdx.x;
  if (e < NE) {
    unsigned d = (unsigned)dst[e];
    if (d < (unsigned)NN) atomicAdd(&cnt[d], 1u);
  }
}

__global__ void inv_k(const unsigned* __restrict__ cnt, float* __restrict__ inv) {
  int n = blockIdx.x * blockDim.x + threadIdx.x;
  if (n < NN) inv[n] = 1.0f / fmaxf((float)cnt[n], 1.0f);
}

__global__ __launch_bounds__(1024) void scan_k(const unsigned* __restrict__ cnt,
                                               unsigned* __restrict__ rowptr) {
  __shared__ unsigned s[1024];
  __shared__ unsigned carry;
  if (threadIdx.x == 0) carry = 0;
  __syncthreads();
  for (int base = 0; base < NN; base += 1024) {
    int i = base + threadIdx.x;
    unsigned v = (i < NN) ? cnt[i] : 0u;
    s[threadIdx.x] = v;
    __syncthreads();
    for (int off = 1; off < 1024; off <<= 1) {
      unsigned t = (threadIdx.x >= (unsigned)off) ? s[threadIdx.x - off] : 0u;
      __syncthreads();
      s[threadIdx.x] += t;
      __syncthreads();
    }
    if (i < NN) rowptr[i] = carry + (s[threadIdx.x] - v);
    __syncthreads();
    if (threadIdx.x == 1023) carry += s[1023];
    __syncthreads();
  }
  if (threadIdx.x == 0) rowptr[NN] = carry;
}

__global__ void fill_k(const int* __restrict__ src, const int* __restrict__ dst,
                       const unsigned* __restrict__ rowptr, unsigned* __restrict__ cursor,
                       int* __restrict__ esrc) {
  int e = blockIdx.x * blockDim.x + threadIdx.x;
  if (e >= NE) return;
  unsigned d = (unsigned)dst[e];
  if (d >= (unsigned)NN) return;
  unsigned pos = atomicAdd(&cursor[d], 1u);
  esrc[rowptr[d] + pos] = src[e];
}

// ---------------- gathers (bf16 payload, fp32 accumulate) ----------------
__global__ __launch_bounds__(256) void gather_mean_k(
    const int* __restrict__ esrc, const unsigned* __restrict__ rowptr,
    const float* __restrict__ inv, const unsigned* __restrict__ xb,
    unsigned* __restrict__ meanb) {
  int node = blockIdx.x * 4 + (threadIdx.x >> 6);
  if (node >= NN) return;
  int lane = threadIdx.x & 63;
  unsigned beg = rowptr[node], end = rowptr[node + 1];
  float ax = 0.f, ay = 0.f;
  unsigned t = beg;
  for (; t + 4 <= end; t += 4) {
    int s0 = esrc[t], s1 = esrc[t + 1], s2 = esrc[t + 2], s3 = esrc[t + 3];
    unsigned v0 = xb[(size_t)s0 * 64 + lane];
    unsigned v1 = xb[(size_t)s1 * 64 + lane];
    unsigned v2 = xb[(size_t)s2 * 64 + lane];
    unsigned v3 = xb[(size_t)s3 * 64 + lane];
    ax += (bflo(v0) + bflo(v1)) + (bflo(v2) + bflo(v3));
    ay += (bfhi(v0) + bfhi(v1)) + (bfhi(v2) + bfhi(v3));
  }
  for (; t < end; ++t) {
    unsigned v0 = xb[(size_t)esrc[t] * 64 + lane];
    ax += bflo(v0); ay += bfhi(v0);
  }
  float sc = inv[node];
  meanb[(size_t)node * 64 + lane] =
      (unsigned)f2bf(ax * sc) | ((unsigned)f2bf(ay * sc) << 16);
}

__global__ __launch_bounds__(256) void gather_add_k(
    const int* __restrict__ esrc, const unsigned* __restrict__ rowptr,
    const float* __restrict__ inv, const unsigned* __restrict__ P,
    float* __restrict__ out) {
  int node = blockIdx.x * 4 + (threadIdx.x >> 6);
  if (node >= NN) return;
  int lane = threadIdx.x & 63;
  unsigned beg = rowptr[node], end = rowptr[node + 1];
  float ax = 0.f, ay = 0.f;
  unsigned t = beg;
  for (; t + 4 <= end; t += 4) {
    int s0 = esrc[t], s1 = esrc[t + 1], s2 = esrc[t + 2], s3 = esrc[t + 3];
    unsigned v0 = P[(size_t)s0 * 64 + lane];
    unsigned v1 = P[(size_t)s1 * 64 + lane];
    unsigned v2 = P[(size_t)s2 * 64 + lane];
    unsigned v3 = P[(size_t)s3 * 64 + lane];
    ax += (bflo(v0) + bflo(v1)) + (bflo(v2) + bflo(v3));
    ay += (bfhi(v0) + bfhi(v1)) + (bfhi(v2) + bfhi(v3));
  }
  for (; t < end; ++t) {
    unsigned v0 = P[(size_t)esrc[t] * 64 + lane];
    ax += bflo(v0); ay += bfhi(v0);
  }
  float sc = inv[node];
  float2* O = (float2*)out;
  float2 o = O[(size_t)node * 64 + lane];
  o.x += ax * sc;
  o.y += ay * sc;
  O[(size_t)node * 64 + lane] = o;
}

// ---------------- MFMA GEMMs: 128x128 tile, 4 waves x 64x64, BK=64 ----------------
// LDS: [128 rows][64 bf16], 128B rows, byte_in_row = (chunk*16) ^ ((row&7)<<4),
// identical on write and read (both-sides-or-neither).
#define BM 128
#define BN 128
#define BK 64

__global__ __launch_bounds__(256) void mgemm1_k(
    const unsigned short* __restrict__ xb, const unsigned short* __restrict__ meanb,
    const unsigned short* __restrict__ W1t, const float* __restrict__ b1,
    unsigned short* __restrict__ h) {
  __shared__ __align__(16) char As[BM * BK * 2];
  __shared__ __align__(16) char Bs[BN * BK * 2];
  const int tid = threadIdx.x;
  const int lane = tid & 63, wid = tid >> 6;
  const int wm = (wid >> 1) * 64, wn = (wid & 1) * 64;
  const int r16 = lane & 15, g = lane >> 4;
  const int m0 = blockIdx.x * BM;
  const int j0 = blockIdx.y * BN;

  f32x4 acc[4][4] = {};

  for (int k0 = 0; k0 < 256; k0 += BK) {
    const unsigned short* Ag = (k0 < 128) ? (xb + k0) : (meanb + (k0 - 128));
#pragma unroll
    for (int p = 0; p < 4; ++p) {
      int id = p * 256 + tid;
      int r = id >> 3, cb = id & 7;
      int grow = m0 + r;
      short8 v = {};
      if (grow < NN) v = *(const short8*)(Ag + (size_t)grow * 128 + cb * 8);
      *(short8*)(As + r * 128 + ((cb * 16) ^ ((r & 7) << 4))) = v;
    }
#pragma unroll
    for (int p = 0; p < 4; ++p) {
      int id = p * 256 + tid;
      int r = id >> 3, cb = id & 7;
      short8 v = *(const short8*)(W1t + (size_t)(j0 + r) * 256 + k0 + cb * 8);
      *(short8*)(Bs + r * 128 + ((cb * 16) ^ ((r & 7) << 4))) = v;
    }
    __syncthreads();
#pragma unroll
    for (int ks = 0; ks < 2; ++ks) {
      short8 af[4], bf[4];
#pragma unroll
      for (int f = 0; f < 4; ++f) {
        int ar = wm + f * 16 + r16;
        af[f] = *(const short8*)(As + ar * 128 + ((ks * 64 + g * 16) ^ ((ar & 7) << 4)));
        int br = wn + f * 16 + r16;
        bf[f] = *(const short8*)(Bs + br * 128 + ((ks * 64 + g * 16) ^ ((br & 7) << 4)));
      }
#pragma unroll
      for (int i = 0; i < 4; ++i)
#pragma unroll
        for (int j = 0; j < 4; ++j)
          acc[i][j] = __builtin_amdgcn_mfma_f32_16x16x32_bf16(af[i], bf[j], acc[i][j], 0, 0, 0);
    }
    __syncthreads();
  }

#pragma unroll
  for (int i = 0; i < 4; ++i)
#pragma unroll
    for (int j = 0; j < 4; ++j) {
      int col = j0 + wn + j * 16 + r16;
      float bias = b1[col];
#pragma unroll
      for (int q = 0; q < 4; ++q) {
        int row = m0 + wm + i * 16 + g * 4 + q;
        if (row < NN) {
          float v = fmaxf(acc[i][j][q] + bias, 0.f);
          v *= dropout_scale((unsigned)row * 256u + (unsigned)col);
          h[(size_t)row * 256 + col] = f2bf(v);
        }
      }
    }
}

__global__ __launch_bounds__(256) void mgemm2_k(
    const unsigned short* __restrict__ h, const unsigned short* __restrict__ W2t,
    const float* __restrict__ b2, unsigned short* __restrict__ P,
    float* __restrict__ out) {
  __shared__ __align__(16) char As[BM * BK * 2];
  __shared__ __align__(16) char Bs[BN * BK * 2];
  const int tid = threadIdx.x;
  const int lane = tid & 63, wid = tid >> 6;
  const int wm = (wid >> 1) * 64, wn = (wid & 1) * 64;
  const int r16 = lane & 15, g = lane >> 4;
  const int m0 = blockIdx.x * BM;
  const int j0 = blockIdx.y * BN;

  f32x4 acc[4][4] = {};

  for (int k0 = 0; k0 < 256; k0 += BK) {
#pragma unroll
    for (int p = 0; p < 4; ++p) {
      int id = p * 256 + tid;
      int r = id >> 3, cb = id & 7;
      int grow = m0 + r;
      short8 v = {};
      if (grow < NN) v = *(const short8*)(h + (size_t)grow * 256 + k0 + cb * 8);
      *(short8*)(As + r * 128 + ((cb * 16) ^ ((r & 7) << 4))) = v;
    }
#pragma unroll
    for (int p = 0; p < 4; ++p) {
      int id = p * 256 + tid;
      int r = id >> 3, cb = id & 7;
      short8 v = *(const short8*)(W2t + (size_t)(j0 + r) * 256 + k0 + cb * 8);
      *(short8*)(Bs + r * 128 + ((cb * 16) ^ ((r & 7) << 4))) = v;
    }
    __syncthreads();
#pragma unroll
    for (int ks = 0; ks < 2; ++ks) {
      short8 af[4], bf[4];
#pragma unroll
      for (int f = 0; f < 4; ++f) {
        int ar = wm + f * 16 + r16;
        af[f] = *(const short8*)(As + ar * 128 + ((ks * 64 + g * 16) ^ ((ar & 7) << 4)));
        int br = wn + f * 16 + r16;
        bf[f] = *(const short8*)(Bs + br * 128 + ((ks * 64 + g * 16) ^ ((br & 7) << 4)));
      }
#pragma unroll
      for (int i = 0; i < 4; ++i)
#pragma unroll
        for (int j = 0; j < 4; ++j)
          acc[i][j] = __builtin_amdgcn_mfma_f32_16x16x32_bf16(af[i], bf[j], acc[i][j], 0, 0, 0);
    }
    __syncthreads();
  }

#pragma unroll
  for (int i = 0; i < 4; ++i)
#pragma unroll
    for (int j = 0; j < 4; ++j) {
      int col = wn + j * 16 + r16;  // 0..127 within this j-half
#pragma unroll
      for (int q = 0; q < 4; ++q) {
        int row = m0 + wm + i * 16 + g * 4 + q;
        if (row < NN) {
          if (j0 == 0) {
            P[(size_t)row * 128 + col] = f2bf(acc[i][j][q]);
          } else {
            out[(size_t)row * 128 + col] = acc[i][j][q] + b2[col];
          }
        }
      }
    }
}

// ---------------- launch ----------------
extern "C" void kernel_launch(void* const* d_in, const int* in_sizes, int n_in,
                              void* d_out, int out_size, void* d_ws, size_t ws_size,
                              hipStream_t stream) {
  const float* x   = (const float*)d_in[0];
  const int*   ei  = (const int*)d_in[1];
  const float* Wl1 = (const float*)d_in[2];
  const float* Wr1 = (const float*)d_in[3];
  const float* b1  = (const float*)d_in[4];
  const float* Wl2 = (const float*)d_in[5];
  const float* Wr2 = (const float*)d_in[6];
  const float* b2  = (const float*)d_in[7];
  float* out = (float*)d_out;

  const int* src = ei;
  const int* dst = ei + NE;

  // workspace layout — NO OVERLAPS (sizes in comments), peak ~71.5 MB:
  char* ws = (char*)d_ws;
  unsigned*       rowptr = (unsigned*)ws;                      // 0x0       + 200,004
  float*          inv    = (float*)(ws + 0x40000);             // 0x40000   + 200,000
  unsigned*       cnt    = (unsigned*)(ws + 0x80000);          // 0x80000   + 200,000
  int*            esrc   = (int*)(ws + 0xC0000);               // 0xC0000   + 3,200,000 -> 0x3CD000
  unsigned short* W1t    = (unsigned short*)(ws + 0x400000);   // 0x400000  + 0x20000
  unsigned short* W2t    = (unsigned short*)(ws + 0x420000);   // 0x420000  + 0x20000
  unsigned short* xb     = (unsigned short*)(ws + 0x500000);   // 0x500000  + 0xC35000 -> 0x1135000
  unsigned short* meanb  = (unsigned short*)(ws + 0x1200000);  // 0x1200000 + 0xC35000 -> 0x1E35000
  unsigned short* h      = (unsigned short*)(ws + 0x1F00000);  // 0x1F00000 + 0x186A000 -> 0x376A000
  unsigned short* P      = (unsigned short*)(ws + 0x3800000);  // 0x3800000 + 0xC35000 -> 0x4435000

  const int TPB = 256;

  // prep: bf16 conversions + weight packing
  cvtx_k<<<(NN * 128 / 4 + TPB - 1) / TPB, TPB, 0, stream>>>((const float4*)x, (uint2*)xb, NN * 128 / 4);
  mkw1_k<<<256, TPB, 0, stream>>>(Wl1, Wr1, W1t);
  mkw2_k<<<256, TPB, 0, stream>>>(Wl2, Wr2, W2t);

  // CSR build
  zero4_k<<<(NN * 4 / 16 + TPB - 1) / TPB, TPB, 0, stream>>>((float4*)cnt, NN * 4 / 16);
  count_k<<<(NE + TPB - 1) / TPB, TPB, 0, stream>>>(dst, cnt);
  inv_k<<<(NN + TPB - 1) / TPB, TPB, 0, stream>>>(cnt, inv);
  scan_k<<<1, 1024, 0, stream>>>(cnt, rowptr);
  zero4_k<<<(NN * 4 / 16 + TPB - 1) / TPB, TPB, 0, stream>>>((float4*)cnt, NN * 4 / 16);
  fill_k<<<(NE + TPB - 1) / TPB, TPB, 0, stream>>>(src, dst, rowptr, cnt, esrc);

  // layer 1
  gather_mean_k<<<(NN + 3) / 4, TPB, 0, stream>>>(esrc, rowptr, inv, (const unsigned*)xb, (unsigned*)meanb);
  dim3 g1((NN + BM - 1) / BM, 256 / BN);
  mgemm1_k<<<g1, TPB, 0, stream>>>(xb, meanb, W1t, b1, h);

  // layer 2
  mgemm2_k<<<g1, TPB, 0, stream>>>(h, W2t, b2, P, out);
  gather_add_k<<<(NN + 3) / 4, TPB, 0, stream>>>(esrc, rowptr, inv, (const unsigned*)P, out);
}

// Round 6
// 263.277 us; speedup vs baseline: 12.2114x; 1.2874x over previous
//
#include <hip/hip_runtime.h>

#define NN 50000
#define NE 800000

typedef __attribute__((ext_vector_type(8))) short short8;
typedef __attribute__((ext_vector_type(4))) float f32x4;

#define SCAN_NB ((NN + 1023) / 1024)  // 49 blocks

// ---------------- bf16 helpers (RNE) ----------------
__device__ __forceinline__ unsigned short f2bf(float f) {
  union { float f; unsigned u; } v; v.f = f;
  unsigned r = (v.u + 0x7FFFu + ((v.u >> 16) & 1u)) >> 16;
  return (unsigned short)r;
}
__device__ __forceinline__ float bflo(unsigned u) {
  union { unsigned x; float f; } v; v.x = u << 16; return v.f;
}
__device__ __forceinline__ float bfhi(unsigned u) {
  union { unsigned x; float f; } v; v.x = u & 0xFFFF0000u; return v.f;
}

// ---------------- threefry2x32, JAX partitionable, key = (0, 42) ----------------
__device__ __forceinline__ unsigned tf_rotl(unsigned x, int r) {
  return (x << r) | (x >> (32 - r));
}
__device__ __forceinline__ void threefry_0_42(unsigned x0, unsigned x1,
                                              unsigned& o0, unsigned& o1) {
  const unsigned k0 = 0u, k1 = 42u;
  const unsigned k2 = k0 ^ k1 ^ 0x1BD11BDAu;
  x0 += k0; x1 += k1;
#define TF_R(r) { x0 += x1; x1 = tf_rotl(x1, (r)); x1 ^= x0; }
  TF_R(13) TF_R(15) TF_R(26) TF_R(6)
  x0 += k1; x1 += k2 + 1u;
  TF_R(17) TF_R(29) TF_R(16) TF_R(24)
  x0 += k2; x1 += k0 + 2u;
  TF_R(13) TF_R(15) TF_R(26) TF_R(6)
  x0 += k0; x1 += k1 + 3u;
  TF_R(17) TF_R(29) TF_R(16) TF_R(24)
  x0 += k1; x1 += k2 + 4u;
  TF_R(13) TF_R(15) TF_R(26) TF_R(6)
  x0 += k2; x1 += k0 + 5u;
#undef TF_R
  o0 = x0; o1 = x1;
}
__device__ __forceinline__ float dropout_scale(unsigned flat) {
  unsigned o0, o1;
  threefry_0_42(0u, flat, o0, o1);
  unsigned bits = o0 ^ o1;
  float u = __uint_as_float((bits >> 9) | 0x3f800000u) - 1.0f;
  return (u < 0.9f) ? (1.0f / 0.9f) : 0.0f;
}

// ---------------- prep: conversions / weight packing ----------------
__global__ void cvtx_k(const float4* __restrict__ x, uint2* __restrict__ xb, int n4) {
  int i = blockIdx.x * 256 + threadIdx.x;
  if (i >= n4) return;
  float4 v = x[i];
  uint2 o;
  o.x = (unsigned)f2bf(v.x) | ((unsigned)f2bf(v.y) << 16);
  o.y = (unsigned)f2bf(v.z) | ((unsigned)f2bf(v.w) << 16);
  xb[i] = o;
}

// combined weight packer: idx<65536 -> W1t, else W2t
// W1t[n][k]: k<128 -> Wr1[k][n], else Wl1[k-128][n]
// W2t[n][k]: n<128 -> Wl2[k][n], else Wr2[k][n-128]
__global__ void mkw_k(const float* __restrict__ Wl1, const float* __restrict__ Wr1,
                      const float* __restrict__ Wl2, const float* __restrict__ Wr2,
                      unsigned short* __restrict__ W1t, unsigned short* __restrict__ W2t) {
  int gid = blockIdx.x * 256 + threadIdx.x;  // 131072
  int idx = gid & 65535;
  int n = idx >> 8, k = idx & 255;
  if (gid < 65536) {
    float v = (k < 128) ? Wr1[(size_t)k * 256 + n] : Wl1[(size_t)(k - 128) * 256 + n];
    W1t[idx] = f2bf(v);
  } else {
    float v = (n < 128) ? Wl2[(size_t)k * 128 + n] : Wr2[(size_t)k * 128 + (n - 128)];
    W2t[idx] = f2bf(v);
  }
}

// ---------------- CSR build ----------------
__global__ void zero4_k(float4* p, int n4) {
  int i = blockIdx.x * blockDim.x + threadIdx.x;
  if (i < n4) p[i] = make_float4(0.f, 0.f, 0.f, 0.f);
}

__global__ void count_k(const int* __restrict__ dst, unsigned* __restrict__ cnt) {
  int e = blockIdx.x * blockDim.x + threadIdx.x;
  if (e < NE) {
    unsigned d = (unsigned)dst[e];
    if (d < (unsigned)NN) atomicAdd(&cnt[d], 1u);
  }
}

__global__ void inv_k(const unsigned* __restrict__ cnt, float* __restrict__ inv) {
  int n = blockIdx.x * blockDim.x + threadIdx.x;
  if (n < NN) inv[n] = 1.0f / fmaxf((float)cnt[n], 1.0f);
}

// two-level scan: A) block-local exclusive scan + block sums
__global__ __launch_bounds__(1024) void scanA_k(const unsigned* __restrict__ cnt,
                                                unsigned* __restrict__ rowptr,
                                                unsigned* __restrict__ bsum) {
  __shared__ unsigned s[1024];
  int i = blockIdx.x * 1024 + threadIdx.x;
  unsigned v = (i < NN) ? cnt[i] : 0u;
  s[threadIdx.x] = v;
  __syncthreads();
  for (int off = 1; off < 1024; off <<= 1) {
    unsigned t = (threadIdx.x >= (unsigned)off) ? s[threadIdx.x - off] : 0u;
    __syncthreads();
    s[threadIdx.x] += t;
    __syncthreads();
  }
  if (i < NN) rowptr[i] = s[threadIdx.x] - v;
  if (threadIdx.x == 1023) bsum[blockIdx.x] = s[1023];
}

// C) add block offsets (computed in-wave over <=64 block sums), zero cnt for
// reuse as fill cursor, and write rowptr[NN]
__global__ __launch_bounds__(1024) void scanC_k(unsigned* __restrict__ rowptr,
                                                const unsigned* __restrict__ bsum,
                                                unsigned* __restrict__ cnt) {
  __shared__ unsigned off_s;
  if (threadIdx.x < 64) {
    unsigned v = (threadIdx.x < blockIdx.x) ? bsum[threadIdx.x] : 0u;
#pragma unroll
    for (int o = 1; o < 64; o <<= 1) v += __shfl_xor(v, o);
    if (threadIdx.x == 0) off_s = v;
  }
  __syncthreads();
  unsigned off = off_s;
  int i = blockIdx.x * 1024 + threadIdx.x;
  if (i < NN) {
    rowptr[i] += off;
    cnt[i] = 0;  // becomes fill cursor
  }
  if (blockIdx.x == SCAN_NB - 1 && threadIdx.x == 0)
    rowptr[NN] = off + bsum[SCAN_NB - 1];
}

__global__ void fill_k(const int* __restrict__ src, const int* __restrict__ dst,
                       const unsigned* __restrict__ rowptr, unsigned* __restrict__ cursor,
                       int* __restrict__ esrc) {
  int e = blockIdx.x * blockDim.x + threadIdx.x;
  if (e >= NE) return;
  unsigned d = (unsigned)dst[e];
  if (d >= (unsigned)NN) return;
  unsigned pos = atomicAdd(&cursor[d], 1u);
  esrc[rowptr[d] + pos] = src[e];
}

// ---------------- gathers (bf16 payload, fp32 accumulate) ----------------
__global__ __launch_bounds__(256) void gather_mean_k(
    const int* __restrict__ esrc, const unsigned* __restrict__ rowptr,
    const float* __restrict__ inv, const unsigned* __restrict__ xb,
    unsigned* __restrict__ meanb) {
  int node = blockIdx.x * 4 + (threadIdx.x >> 6);
  if (node >= NN) return;
  int lane = threadIdx.x & 63;
  unsigned beg = rowptr[node], end = rowptr[node + 1];
  float ax = 0.f, ay = 0.f;
  unsigned t = beg;
  for (; t + 4 <= end; t += 4) {
    int s0 = esrc[t], s1 = esrc[t + 1], s2 = esrc[t + 2], s3 = esrc[t + 3];
    unsigned v0 = xb[(size_t)s0 * 64 + lane];
    unsigned v1 = xb[(size_t)s1 * 64 + lane];
    unsigned v2 = xb[(size_t)s2 * 64 + lane];
    unsigned v3 = xb[(size_t)s3 * 64 + lane];
    ax += (bflo(v0) + bflo(v1)) + (bflo(v2) + bflo(v3));
    ay += (bfhi(v0) + bfhi(v1)) + (bfhi(v2) + bfhi(v3));
  }
  for (; t < end; ++t) {
    unsigned v0 = xb[(size_t)esrc[t] * 64 + lane];
    ax += bflo(v0); ay += bfhi(v0);
  }
  float sc = inv[node];
  meanb[(size_t)node * 64 + lane] =
      (unsigned)f2bf(ax * sc) | ((unsigned)f2bf(ay * sc) << 16);
}

__global__ __launch_bounds__(256) void gather_add_k(
    const int* __restrict__ esrc, const unsigned* __restrict__ rowptr,
    const float* __restrict__ inv, const unsigned* __restrict__ P,
    float* __restrict__ out) {
  int node = blockIdx.x * 4 + (threadIdx.x >> 6);
  if (node >= NN) return;
  int lane = threadIdx.x & 63;
  unsigned beg = rowptr[node], end = rowptr[node + 1];
  float ax = 0.f, ay = 0.f;
  unsigned t = beg;
  for (; t + 4 <= end; t += 4) {
    int s0 = esrc[t], s1 = esrc[t + 1], s2 = esrc[t + 2], s3 = esrc[t + 3];
    unsigned v0 = P[(size_t)s0 * 64 + lane];
    unsigned v1 = P[(size_t)s1 * 64 + lane];
    unsigned v2 = P[(size_t)s2 * 64 + lane];
    unsigned v3 = P[(size_t)s3 * 64 + lane];
    ax += (bflo(v0) + bflo(v1)) + (bflo(v2) + bflo(v3));
    ay += (bfhi(v0) + bfhi(v1)) + (bfhi(v2) + bfhi(v3));
  }
  for (; t < end; ++t) {
    unsigned v0 = P[(size_t)esrc[t] * 64 + lane];
    ax += bflo(v0); ay += bfhi(v0);
  }
  float sc = inv[node];
  float2* O = (float2*)out;
  float2 o = O[(size_t)node * 64 + lane];
  o.x += ax * sc;
  o.y += ay * sc;
  O[(size_t)node * 64 + lane] = o;
}

// ---------------- MFMA GEMMs: 128x128 tile, 4 waves x 64x64, BK=64 ----------------
// LDS: [128 rows][64 bf16], 128B rows, byte_in_row = (chunk*16) ^ ((row&7)<<4),
// identical on write and read (both-sides-or-neither).
#define BM 128
#define BN 128
#define BK 64

__global__ __launch_bounds__(256) void mgemm1_k(
    const unsigned short* __restrict__ xb, const unsigned short* __restrict__ meanb,
    const unsigned short* __restrict__ W1t, const float* __restrict__ b1,
    unsigned short* __restrict__ h) {
  __shared__ __align__(16) char As[BM * BK * 2];
  __shared__ __align__(16) char Bs[BN * BK * 2];
  const int tid = threadIdx.x;
  const int lane = tid & 63, wid = tid >> 6;
  const int wm = (wid >> 1) * 64, wn = (wid & 1) * 64;
  const int r16 = lane & 15, g = lane >> 4;
  const int m0 = blockIdx.x * BM;
  const int j0 = blockIdx.y * BN;

  f32x4 acc[4][4] = {};

  for (int k0 = 0; k0 < 256; k0 += BK) {
    const unsigned short* Ag = (k0 < 128) ? (xb + k0) : (meanb + (k0 - 128));
#pragma unroll
    for (int p = 0; p < 4; ++p) {
      int id = p * 256 + tid;
      int r = id >> 3, cb = id & 7;
      int grow = m0 + r;
      short8 v = {};
      if (grow < NN) v = *(const short8*)(Ag + (size_t)grow * 128 + cb * 8);
      *(short8*)(As + r * 128 + ((cb * 16) ^ ((r & 7) << 4))) = v;
    }
#pragma unroll
    for (int p = 0; p < 4; ++p) {
      int id = p * 256 + tid;
      int r = id >> 3, cb = id & 7;
      short8 v = *(const short8*)(W1t + (size_t)(j0 + r) * 256 + k0 + cb * 8);
      *(short8*)(Bs + r * 128 + ((cb * 16) ^ ((r & 7) << 4))) = v;
    }
    __syncthreads();
#pragma unroll
    for (int ks = 0; ks < 2; ++ks) {
      short8 af[4], bf[4];
#pragma unroll
      for (int f = 0; f < 4; ++f) {
        int ar = wm + f * 16 + r16;
        af[f] = *(const short8*)(As + ar * 128 + ((ks * 64 + g * 16) ^ ((ar & 7) << 4)));
        int br = wn + f * 16 + r16;
        bf[f] = *(const short8*)(Bs + br * 128 + ((ks * 64 + g * 16) ^ ((br & 7) << 4)));
      }
#pragma unroll
      for (int i = 0; i < 4; ++i)
#pragma unroll
        for (int j = 0; j < 4; ++j)
          acc[i][j] = __builtin_amdgcn_mfma_f32_16x16x32_bf16(af[i], bf[j], acc[i][j], 0, 0, 0);
    }
    __syncthreads();
  }

#pragma unroll
  for (int i = 0; i < 4; ++i)
#pragma unroll
    for (int j = 0; j < 4; ++j) {
      int col = j0 + wn + j * 16 + r16;
      float bias = b1[col];
#pragma unroll
      for (int q = 0; q < 4; ++q) {
        int row = m0 + wm + i * 16 + g * 4 + q;
        if (row < NN) {
          float v = fmaxf(acc[i][j][q] + bias, 0.f);
          v *= dropout_scale((unsigned)row * 256u + (unsigned)col);
          h[(size_t)row * 256 + col] = f2bf(v);
        }
      }
    }
}

__global__ __launch_bounds__(256) void mgemm2_k(
    const unsigned short* __restrict__ h, const unsigned short* __restrict__ W2t,
    const float* __restrict__ b2, unsigned short* __restrict__ P,
    float* __restrict__ out) {
  __shared__ __align__(16) char As[BM * BK * 2];
  __shared__ __align__(16) char Bs[BN * BK * 2];
  const int tid = threadIdx.x;
  const int lane = tid & 63, wid = tid >> 6;
  const int wm = (wid >> 1) * 64, wn = (wid & 1) * 64;
  const int r16 = lane & 15, g = lane >> 4;
  const int m0 = blockIdx.x * BM;
  const int j0 = blockIdx.y * BN;

  f32x4 acc[4][4] = {};

  for (int k0 = 0; k0 < 256; k0 += BK) {
#pragma unroll
    for (int p = 0; p < 4; ++p) {
      int id = p * 256 + tid;
      int r = id >> 3, cb = id & 7;
      int grow = m0 + r;
      short8 v = {};
      if (grow < NN) v = *(const short8*)(h + (size_t)grow * 256 + k0 + cb * 8);
      *(short8*)(As + r * 128 + ((cb * 16) ^ ((r & 7) << 4))) = v;
    }
#pragma unroll
    for (int p = 0; p < 4; ++p) {
      int id = p * 256 + tid;
      int r = id >> 3, cb = id & 7;
      short8 v = *(const short8*)(W2t + (size_t)(j0 + r) * 256 + k0 + cb * 8);
      *(short8*)(Bs + r * 128 + ((cb * 16) ^ ((r & 7) << 4))) = v;
    }
    __syncthreads();
#pragma unroll
    for (int ks = 0; ks < 2; ++ks) {
      short8 af[4], bf[4];
#pragma unroll
      for (int f = 0; f < 4; ++f) {
        int ar = wm + f * 16 + r16;
        af[f] = *(const short8*)(As + ar * 128 + ((ks * 64 + g * 16) ^ ((ar & 7) << 4)));
        int br = wn + f * 16 + r16;
        bf[f] = *(const short8*)(Bs + br * 128 + ((ks * 64 + g * 16) ^ ((br & 7) << 4)));
      }
#pragma unroll
      for (int i = 0; i < 4; ++i)
#pragma unroll
        for (int j = 0; j < 4; ++j)
          acc[i][j] = __builtin_amdgcn_mfma_f32_16x16x32_bf16(af[i], bf[j], acc[i][j], 0, 0, 0);
    }
    __syncthreads();
  }

#pragma unroll
  for (int i = 0; i < 4; ++i)
#pragma unroll
    for (int j = 0; j < 4; ++j) {
      int col = wn + j * 16 + r16;  // 0..127 within this j-half
#pragma unroll
      for (int q = 0; q < 4; ++q) {
        int row = m0 + wm + i * 16 + g * 4 + q;
        if (row < NN) {
          if (j0 == 0) {
            P[(size_t)row * 128 + col] = f2bf(acc[i][j][q]);
          } else {
            out[(size_t)row * 128 + col] = acc[i][j][q] + b2[col];
          }
        }
      }
    }
}

// ---------------- launch ----------------
extern "C" void kernel_launch(void* const* d_in, const int* in_sizes, int n_in,
                              void* d_out, int out_size, void* d_ws, size_t ws_size,
                              hipStream_t stream) {
  const float* x   = (const float*)d_in[0];
  const int*   ei  = (const int*)d_in[1];
  const float* Wl1 = (const float*)d_in[2];
  const float* Wr1 = (const float*)d_in[3];
  const float* b1  = (const float*)d_in[4];
  const float* Wl2 = (const float*)d_in[5];
  const float* Wr2 = (const float*)d_in[6];
  const float* b2  = (const float*)d_in[7];
  float* out = (float*)d_out;

  const int* src = ei;
  const int* dst = ei + NE;

  // workspace layout — NO OVERLAPS, peak ~71.5 MB:
  char* ws = (char*)d_ws;
  unsigned*       rowptr = (unsigned*)ws;                      // 0x0       + 200,004
  float*          inv    = (float*)(ws + 0x40000);             // 0x40000   + 200,000
  unsigned*       cnt    = (unsigned*)(ws + 0x80000);          // 0x80000   + 200,000
  unsigned*       bsum   = (unsigned*)(ws + 0xB8000);          // 0xB8000   + 196 (within cnt page slack)
  int*            esrc   = (int*)(ws + 0xC0000);               // 0xC0000   + 3,200,000 -> 0x3CD000
  unsigned short* W1t    = (unsigned short*)(ws + 0x400000);   // 0x400000  + 0x20000
  unsigned short* W2t    = (unsigned short*)(ws + 0x420000);   // 0x420000  + 0x20000
  unsigned short* xb     = (unsigned short*)(ws + 0x500000);   // 0x500000  + 0xC35000 -> 0x1135000
  unsigned short* meanb  = (unsigned short*)(ws + 0x1200000);  // 0x1200000 + 0xC35000 -> 0x1E35000
  unsigned short* h      = (unsigned short*)(ws + 0x1F00000);  // 0x1F00000 + 0x186A000 -> 0x376A000
  unsigned short* P      = (unsigned short*)(ws + 0x3800000);  // 0x3800000 + 0xC35000 -> 0x4435000

  const int TPB = 256;

  // prep: bf16 conversions + weight packing
  cvtx_k<<<(NN * 128 / 4 + TPB - 1) / TPB, TPB, 0, stream>>>((const float4*)x, (uint2*)xb, NN * 128 / 4);
  mkw_k<<<512, TPB, 0, stream>>>(Wl1, Wr1, Wl2, Wr2, W1t, W2t);

  // CSR build
  zero4_k<<<(NN * 4 / 16 + TPB - 1) / TPB, TPB, 0, stream>>>((float4*)cnt, NN * 4 / 16);
  count_k<<<(NE + TPB - 1) / TPB, TPB, 0, stream>>>(dst, cnt);
  inv_k<<<(NN + TPB - 1) / TPB, TPB, 0, stream>>>(cnt, inv);
  scanA_k<<<SCAN_NB, 1024, 0, stream>>>(cnt, rowptr, bsum);
  scanC_k<<<SCAN_NB, 1024, 0, stream>>>(rowptr, bsum, cnt);  // also zeroes cnt -> cursor
  fill_k<<<(NE + TPB - 1) / TPB, TPB, 0, stream>>>(src, dst, rowptr, cnt, esrc);

  // layer 1
  gather_mean_k<<<(NN + 3) / 4, TPB, 0, stream>>>(esrc, rowptr, inv, (const unsigned*)xb, (unsigned*)meanb);
  dim3 g1((NN + BM - 1) / BM, 256 / BN);
  mgemm1_k<<<g1, TPB, 0, stream>>>(xb, meanb, W1t, b1, h);

  // layer 2
  mgemm2_k<<<g1, TPB, 0, stream>>>(h, W2t, b2, P, out);
  gather_add_k<<<(NN + 3) / 4, TPB, 0, stream>>>(esrc, rowptr, inv, (const unsigned*)P, out);
}